// Round 15
// baseline (81.348 us; speedup 1.0000x reference)
//
#include <hip/hip_runtime.h>
#include <hip/hip_bf16.h>

typedef __attribute__((ext_vector_type(4))) float  f32x4;
typedef __attribute__((ext_vector_type(8))) short  bf16x8;
typedef __attribute__((ext_vector_type(4))) short  bf16x4v;

#define EPAD 68   // f32 elems per epilogue LDS row
#define AS1 __attribute__((address_space(1)))
#define AS3 __attribute__((address_space(3)))

__device__ __forceinline__ unsigned short f2bf(float f) {
  __hip_bfloat16 h = __float2bfloat16(f);
  unsigned short u; __builtin_memcpy(&u, &h, 2); return u;
}
__device__ __forceinline__ float bf2f(short u) {
  unsigned int w = ((unsigned int)(unsigned short)u) << 16;
  float f; __builtin_memcpy(&f, &w, 4); return f;
}

// Fully-inline sincos. k in f32 (|x|<=~6 -> k exact), reduction in f64
// (tan pole needs ABSOLUTE reduced-arg err < ~6e-9), polys f32.
__device__ __forceinline__ void my_sincos(float xf, float& s_out, float& c_out) {
  const float kf = __builtin_rintf(xf * 0.636619772367581343f);      // x * 2/pi
  const int   q  = (int)kf;
  const double kd = (double)kf;
  double rd = __builtin_fma(-kd, 1.5707963267948966,    (double)xf); // pio2_hi
  rd        = __builtin_fma(-kd, 6.123233995736766e-17, rd);         // pio2_lo
  const float r = (float)rd;
  const float z = r * r;
  const float ps = fmaf(z, fmaf(z, fmaf(z, 2.7183114939898219e-06f,
                                           -1.9839334836096632e-04f),
                                   8.3333293858894632e-03f),
                        -1.6666666641626524e-01f);
  const float sr = fmaf(r * z, ps, r);                               // sin(r)
  const float pc = fmaf(z, fmaf(z, fmaf(z, 2.4390448796277409e-05f,
                                           -1.3886763774609929e-03f),
                                   4.1666623323739063e-02f),
                        -4.9999999725103100e-01f);
  const float cr = fmaf(z, pc, 1.0f);                                // cos(r)
  const bool swap = (q & 1) != 0;
  float s1 = swap ? cr : sr;
  float c1 = swap ? sr : cr;
  if (q & 2)       s1 = -s1;
  if ((q + 1) & 2) c1 = -c1;
  s_out = s1; c_out = c1;
}

// ---- fused prep: blocks 0..255 transpose W -> Wt(bf16); blocks 256+ stream
// x -> xb(bf16) and g = b*sin(x)+c*cos(x)+d*tan(x) -> bf16 (trig hides under
// the memory-bound stream; measured at the BW floor ~22 us).
__global__ __launch_bounds__(256)
void prep_all(const float* __restrict__ W, const float* __restrict__ x,
              const float* __restrict__ bv, const float* __restrict__ cv,
              const float* __restrict__ dv,
              unsigned short* __restrict__ Wt, unsigned short* __restrict__ xb,
              unsigned short* __restrict__ g, int H, int n4) {
  __shared__ float tile[64][65];
  const int t = threadIdx.x;
  if (blockIdx.x < 256) {
    const int blk = blockIdx.x;
    const int n0 = (blk & 15) << 6;
    const int k0 = (blk >> 4) << 6;
    #pragma unroll
    for (int it = 0; it < 4; ++it) {
      int q = it * 256 + t;
      int r = q >> 4, c4 = (q & 15) << 2;
      f32x4 v = *(const f32x4*)&W[(size_t)(k0 + r) * H + n0 + c4];
      tile[r][c4 + 0] = v[0]; tile[r][c4 + 1] = v[1];
      tile[r][c4 + 2] = v[2]; tile[r][c4 + 3] = v[3];
    }
    __syncthreads();
    #pragma unroll
    for (int it = 0; it < 4; ++it) {
      int q = it * 256 + t;
      int r = q >> 4, c4 = (q & 15) << 2;
      bf16x4v o;
      #pragma unroll
      for (int j = 0; j < 4; ++j) o[j] = (short)f2bf(tile[c4 + j][r]);
      *(bf16x4v*)&Wt[(size_t)(n0 + r) * H + k0 + c4] = o;
    }
  } else {
    const int jm = (H >> 2) - 1;             // H pow2: chunk-index mask
    int i = (blockIdx.x - 256) * 256 + t;
    const int stride = ((int)gridDim.x - 256) * 256;
    for (; i < n4; i += stride) {
      f32x4 v = ((const f32x4*)x)[i];
      const int j4 = (i & jm) << 2;
      f32x4 b4 = *(const f32x4*)&bv[j4];
      f32x4 c4 = *(const f32x4*)&cv[j4];
      f32x4 d4 = *(const f32x4*)&dv[j4];
      bf16x4v xo, go;
      #pragma unroll
      for (int e = 0; e < 4; ++e) {
        xo[e] = (short)f2bf(v[e]);
        float s, co;
        my_sincos(v[e], s, co);
        const float tn = s * __builtin_amdgcn_rcpf(co);  // |err| ~0.13 @ pole
        go[e] = (short)f2bf(fmaf(b4[e], s, fmaf(c4[e], co, d4[e] * tn)));
      }
      ((bf16x4v*)xb)[i] = xo;
      ((bf16x4v*)g)[i]  = go;
    }
  }
}

// ---- fallback prep kernels ----
__global__ __launch_bounds__(256)
void transpose_W(const float* __restrict__ W, unsigned short* __restrict__ Wt, int H) {
  __shared__ float tile[64][65];
  const int k0 = blockIdx.y * 64;
  const int n0 = blockIdx.x * 64;
  const int t = threadIdx.x;
  #pragma unroll
  for (int it = 0; it < 4; ++it) {
    int q = it * 256 + t;
    int r = q >> 4, c4 = (q & 15) << 2;
    f32x4 v = *(const f32x4*)&W[(size_t)(k0 + r) * H + n0 + c4];
    tile[r][c4 + 0] = v[0]; tile[r][c4 + 1] = v[1];
    tile[r][c4 + 2] = v[2]; tile[r][c4 + 3] = v[3];
  }
  __syncthreads();
  #pragma unroll
  for (int it = 0; it < 4; ++it) {
    int q = it * 256 + t;
    int r = q >> 4, c4 = (q & 15) << 2;
    bf16x4v o;
    #pragma unroll
    for (int j = 0; j < 4; ++j) o[j] = (short)f2bf(tile[c4 + j][r]);
    *(bf16x4v*)&Wt[(size_t)(n0 + r) * H + k0 + c4] = o;
  }
}
__global__ __launch_bounds__(256)
void cvt_x(const float* __restrict__ x, unsigned short* __restrict__ xb, int n4) {
  int i = blockIdx.x * 256 + threadIdx.x;
  const int stride = gridDim.x * 256;
  for (; i < n4; i += stride) {
    f32x4 v = ((const f32x4*)x)[i];
    bf16x4v o;
    #pragma unroll
    for (int j = 0; j < 4; ++j) o[j] = (short)f2bf(v[j]);
    ((bf16x4v*)xb)[i] = o;
  }
}

// ---- main GEMM: 256x256 tile, 8 waves, 2-phase fine-interleaved pipeline ----
// r14's verified 3-slot / stage(t+2) / counted-vmcnt ledger, with the K-step
// split into 2 phases carrying the m196/m201 fine interleave:
//   phase = { issue ds_reads of this phase's fragment subtile (pure-reg dest)
//             + issue one STAGE half (gload_lds -> vmcnt, NOT lgkmcnt)
//             -> s_barrier (read latency hides under barrier convergence)
//             -> lgkmcnt(0) + sched_barrier(0)   [rule #18]
//             -> setprio(1); 16 pure-reg MFMA; setprio(0) -> s_barrier }
// B-frags are read once per tile (phase A) and reused in phase B.
// vmcnt(4) once per tile (phase B): retires tile t+1's 4 stage loads while
// tile t+2's 4 stay in flight. vmcnt(0) only in the tail.
// Slot-overwrite safety: STAGE_x(t+2) writes slot[(t+2)%3] holding tile t-1,
// whose reads were consumed by MFMAs before t-1's trailing barrier ->
// separated by >=1 barrier from this STAGE. Same argument as r14 (verified).
__global__ __launch_bounds__(512, 2)
void gemm_256(const unsigned short* __restrict__ xb,
              const unsigned short* __restrict__ Wt,
              const unsigned short* __restrict__ g,
              float* __restrict__ out, float S, int H) {
  __shared__ unsigned char smem[98304];             // 3 x 32KB K-tile slots
  float* Es = (float*)smem;                         // epilogue overlay (34.8KB)

  const int tid  = threadIdx.x;
  const int nwg  = gridDim.x;
  const int work = (blockIdx.x & 7) * (nwg >> 3) + (blockIdx.x >> 3);
  const int nbj  = H >> 8;                          // N tiles of 256
  const int bj   = work % nbj;
  const int bi   = work / nbj;
  const int i0   = bi * 256, j0 = bj * 256;
  const int wave = tid >> 6, lane = tid & 63;
  const int wr   = wave >> 2, wc = wave & 3;        // 2(M) x 4(N) wave grid
  const int l16  = lane & 15, lq = lane >> 4;

  // Staging sources (inverse swizzle; r10-verified map).
  const unsigned short *aS0, *aS1, *bS0, *bS1;
  {
    const int D0 = tid * 16,        sup0 = D0 >> 7;
    const int sl0 = ((D0 >> 4) & 7) ^ (sup0 & 7);
    const int r0  = sup0 * 2 + (sl0 >> 2), c0 = (sl0 & 3) << 3;
    const int D1 = 8192 + tid * 16, sup1 = D1 >> 7;
    const int sl1 = ((D1 >> 4) & 7) ^ (sup1 & 7);
    const int r1  = sup1 * 2 + (sl1 >> 2), c1 = (sl1 & 3) << 3;
    aS0 = &xb[(size_t)(i0 + r0) * H + c0];
    aS1 = &xb[(size_t)(i0 + r1) * H + c1];
    bS0 = &Wt[(size_t)(j0 + r0) * H + c0];
    bS1 = &Wt[(size_t)(j0 + r1) * H + c1];
  }

  #define STAGE_A(sl, kOff)                                                     \
    do {                                                                        \
      char* _b = (char*)smem + (sl) * 32768;                                    \
      __builtin_amdgcn_global_load_lds((const AS1 void*)(aS0 + (kOff)),         \
        (AS3 void*)(_b + tid * 16), 16, 0, 0);                                  \
      __builtin_amdgcn_global_load_lds((const AS1 void*)(aS1 + (kOff)),         \
        (AS3 void*)(_b + 8192 + tid * 16), 16, 0, 0);                           \
    } while (0)
  #define STAGE_B(sl, kOff)                                                     \
    do {                                                                        \
      char* _b = (char*)smem + (sl) * 32768;                                    \
      __builtin_amdgcn_global_load_lds((const AS1 void*)(bS0 + (kOff)),         \
        (AS3 void*)(_b + 16384 + tid * 16), 16, 0, 0);                          \
      __builtin_amdgcn_global_load_lds((const AS1 void*)(bS1 + (kOff)),         \
        (AS3 void*)(_b + 24576 + tid * 16), 16, 0, 0);                          \
    } while (0)

  // Fragment read offsets (forward swizzle; r10-verified conflict-free).
  const int slotx = (4 * (l16 & 1) + lq) ^ ((l16 >> 1) & 7);
  const int laneT = (l16 >> 1) * 128 + slotx * 16;
  const int aBase = wr * 8192 + laneT;
  const int bBase = wc * 4096 + laneT;

  f32x4 acc[8][4] = {};

  const int nt = H >> 5;                            // BK = 32
  STAGE_A(0, 0);  STAGE_B(0, 0);                    // tile 0 -> slot 0
  STAGE_A(1, 32); STAGE_B(1, 32);                   // tile 1 -> slot 1
  asm volatile("s_waitcnt vmcnt(4)" ::: "memory");  // tile 0 landed
  __builtin_amdgcn_s_barrier();                     // publish tile 0

  int slot = 0;
  for (int t = 0; t < nt; ++t) {
    const char* Ab = (const char*)smem + slot * 32768;
    const char* Bb = Ab + 16384;
    int s2 = slot + 2; if (s2 >= 3) s2 -= 3;        // slot of tile t+2
    const int k2 = (t + 2) * 32;
    const bool more = (t + 2) < nt;

    // ---- phase A: frags {mi 0-3} x {ni 0-3}, stage A-half of t+2 ----
    bf16x8 afA[4], bfr[4];
    #pragma unroll
    for (int mi = 0; mi < 4; ++mi) afA[mi] = *(const bf16x8*)(Ab + aBase + mi * 1024);
    #pragma unroll
    for (int ni = 0; ni < 4; ++ni) bfr[ni] = *(const bf16x8*)(Bb + bBase + ni * 1024);
    asm volatile("" ::: "memory");                  // pin reads before barrier
    if (more) STAGE_A(s2, k2);
    __builtin_amdgcn_s_barrier();
    asm volatile("s_waitcnt lgkmcnt(0)" ::: "memory");
    __builtin_amdgcn_sched_barrier(0);              // rule #18: pin MFMAs after
    __builtin_amdgcn_s_setprio(1);
    #pragma unroll
    for (int mi = 0; mi < 4; ++mi)
      #pragma unroll
      for (int ni = 0; ni < 4; ++ni)
        acc[mi][ni] = __builtin_amdgcn_mfma_f32_16x16x32_bf16(afA[mi], bfr[ni], acc[mi][ni], 0, 0, 0);
    __builtin_amdgcn_s_setprio(0);
    __builtin_amdgcn_s_barrier();

    // ---- phase B: frags {mi 4-7} x {ni 0-3} (B-frags reused), stage B-half ----
    bf16x8 afB[4];
    #pragma unroll
    for (int mi = 0; mi < 4; ++mi) afB[mi] = *(const bf16x8*)(Ab + aBase + (mi + 4) * 1024);
    asm volatile("" ::: "memory");
    if (more) {
      STAGE_B(s2, k2);
      asm volatile("s_waitcnt vmcnt(4)" ::: "memory");   // retire tile t+1 stages
    } else if (t + 1 < nt) {
      asm volatile("s_waitcnt vmcnt(0)" ::: "memory");   // tail drain
    }
    __builtin_amdgcn_s_barrier();
    asm volatile("s_waitcnt lgkmcnt(0)" ::: "memory");
    __builtin_amdgcn_sched_barrier(0);
    __builtin_amdgcn_s_setprio(1);
    #pragma unroll
    for (int mi = 0; mi < 4; ++mi)
      #pragma unroll
      for (int ni = 0; ni < 4; ++ni)
        acc[mi + 4][ni] = __builtin_amdgcn_mfma_f32_16x16x32_bf16(afB[mi], bfr[ni], acc[mi + 4][ni], 0, 0, 0);
    __builtin_amdgcn_s_setprio(0);
    __builtin_amdgcn_s_barrier();

    slot += 1; if (slot == 3) slot = 0;
  }
  #undef STAGE_A
  #undef STAGE_B
  __syncthreads();                                  // full drain before Es overlay

  // ---- epilogue: per-wave LDS transpose then coalesced f32x4 IO ----
  // C/D fragment layout: col = l16, row = lq*4 + r  [m89-verified]
  float* ep = Es + wave * (16 * EPAD);
  const int rr = lane >> 2;           // 0..15
  const int cq = (lane & 3) * 16;     // 0,16,32,48
  #pragma unroll
  for (int mi = 0; mi < 8; ++mi) {
    #pragma unroll
    for (int ni = 0; ni < 4; ++ni)
      #pragma unroll
      for (int r = 0; r < 4; ++r)
        ep[(lq * 4 + r) * EPAD + ni * 16 + l16] = acc[mi][ni][r];
    // same-wave ds_write -> ds_read: in-order LDS pipe, compiler waits lgkmcnt.
    const int i  = i0 + wr * 128 + mi * 16 + rr;
    const int jb = j0 + wc * 64 + cq;
    float* orow = &out[(size_t)i * H + jb];
    const unsigned short* grow = &g[(size_t)i * H + jb];
    #pragma unroll
    for (int t = 0; t < 4; ++t) {
      f32x4 a = *(const f32x4*)&ep[rr * EPAD + cq + 4 * t];
      bf16x4v gv = *(const bf16x4v*)&grow[4 * t];
      f32x4 o;
      #pragma unroll
      for (int e = 0; e < 4; ++e) o[e] = S * (a[e] + bf2f(gv[e]));
      *(f32x4*)&orow[4 * t] = o;
    }
  }
}

// ---- fallback GEMM (round-6 structure, 256 thr) for small-ws / odd-shape ----
template <int MODE>   // 1: xb staging + trig epi ; 2: f32 staging + trig epi
__global__ __launch_bounds__(256, 2)
void gemm_fb(const float* __restrict__ x, const unsigned short* __restrict__ xb,
             const unsigned short* __restrict__ Wt,
             const float* __restrict__ bv, const float* __restrict__ cv,
             const float* __restrict__ dv, float* __restrict__ out,
             float S, int H) {
  __shared__ unsigned char smem[36864];
  unsigned short* As = (unsigned short*)smem;            // [128][72]
  unsigned short* Bs = As + 128 * 72;
  float*          Es = (float*)smem;

  const int tid  = threadIdx.x;
  const int nwg  = gridDim.x;
  const int work = (nwg % 8 == 0) ? (blockIdx.x & 7) * (nwg >> 3) + (blockIdx.x >> 3)
                                  : blockIdx.x;
  const int nbj  = H / 128;
  const int bj   = work % nbj;
  const int bi   = work / nbj;
  const int i0   = bi * 128, j0 = bj * 128;
  const int wave = tid >> 6, lane = tid & 63;
  const int wr = wave >> 1, wc = wave & 1;
  const int l16 = lane & 15, lq = lane >> 4;

  f32x4 acc[4][4] = {};
  for (int kk = 0; kk < H; kk += 64) {
    if constexpr (MODE == 1) {
      #pragma unroll
      for (int it = 0; it < 4; ++it) {
        int q = it * 256 + tid;
        int r = q >> 3, c8 = (q & 7) << 3;
        *(bf16x8*)&As[r * 72 + c8] = *(const bf16x8*)&xb[(size_t)(i0 + r) * H + kk + c8];
      }
    } else {
      #pragma unroll
      for (int it = 0; it < 8; ++it) {
        int q = it * 256 + tid;
        int r = q >> 4, c4 = (q & 15) << 2;
        f32x4 v = *(const f32x4*)&x[(size_t)(i0 + r) * H + kk + c4];
        bf16x4v o;
        #pragma unroll
        for (int j = 0; j < 4; ++j) o[j] = (short)f2bf(v[j]);
        *(bf16x4v*)&As[r * 72 + c4] = o;
      }
    }
    #pragma unroll
    for (int it = 0; it < 4; ++it) {
      int q = it * 256 + tid;
      int r = q >> 3, c8 = (q & 7) << 3;
      *(bf16x8*)&Bs[r * 72 + c8] = *(const bf16x8*)&Wt[(size_t)(j0 + r) * H + kk + c8];
    }
    __syncthreads();
    #pragma unroll
    for (int s = 0; s < 2; ++s) {
      bf16x8 af[4], bfr[4];
      #pragma unroll
      for (int mi = 0; mi < 4; ++mi)
        af[mi] = *(const bf16x8*)&As[(wr * 64 + mi * 16 + l16) * 72 + s * 32 + lq * 8];
      #pragma unroll
      for (int ni = 0; ni < 4; ++ni)
        bfr[ni] = *(const bf16x8*)&Bs[(wc * 64 + ni * 16 + l16) * 72 + s * 32 + lq * 8];
      #pragma unroll
      for (int mi = 0; mi < 4; ++mi)
        #pragma unroll
        for (int ni = 0; ni < 4; ++ni)
          acc[mi][ni] = __builtin_amdgcn_mfma_f32_16x16x32_bf16(af[mi], bfr[ni], acc[mi][ni], 0, 0, 0);
    }
    __syncthreads();
  }
  float* ep = Es + wave * (16 * EPAD);
  const int rr = lane >> 2;
  const int cq = (lane & 3) * 16;
  #pragma unroll
  for (int mi = 0; mi < 4; ++mi) {
    #pragma unroll
    for (int ni = 0; ni < 4; ++ni)
      #pragma unroll
      for (int r = 0; r < 4; ++r)
        ep[(lq * 4 + r) * EPAD + ni * 16 + l16] = acc[mi][ni][r];
    const int i  = i0 + wr * 64 + mi * 16 + rr;
    const int jb = j0 + wc * 64 + cq;
    const float* xrow = &x[(size_t)i * H + jb];
    float*       orow = &out[(size_t)i * H + jb];
    #pragma unroll
    for (int t = 0; t < 4; ++t) {
      f32x4 a  = *(const f32x4*)&ep[rr * EPAD + cq + 4 * t];
      f32x4 xv = *(const f32x4*)&xrow[4 * t];
      f32x4 b4 = *(const f32x4*)&bv[jb + 4 * t];
      f32x4 c4 = *(const f32x4*)&cv[jb + 4 * t];
      f32x4 d4 = *(const f32x4*)&dv[jb + 4 * t];
      f32x4 o;
      #pragma unroll
      for (int e = 0; e < 4; ++e) {
        float s, co;
        my_sincos(xv[e], s, co);
        const float tanv = s * __builtin_amdgcn_rcpf(co);
        o[e] = S * (fmaf(b4[e], s, a[e]) + fmaf(c4[e], co, d4[e] * tanv));
      }
      *(f32x4*)&orow[4 * t] = o;
    }
  }
}

extern "C" void kernel_launch(void* const* d_in, const int* in_sizes, int n_in,
                              void* d_out, int out_size, void* d_ws, size_t ws_size,
                              hipStream_t stream) {
  const float* x = (const float*)d_in[0];
  const float* W = (const float*)d_in[1];
  const float* b = (const float*)d_in[2];
  const float* c = (const float*)d_in[3];
  const float* d = (const float*)d_in[4];
  float* out = (float*)d_out;
  const int H = in_sizes[2];          // 1024
  const int M = in_sizes[0] / H;      // 16384

  // Scalar RK4 factor: y_final = S * z (ODE linear in y, y0 = 0).
  const int NT = 100;
  float ts[NT];
  const float step = (float)(1.0 / 99.0);
  for (int i = 0; i < NT; ++i) ts[i] = (float)i * step;
  ts[NT - 1] = 1.0f;
  double yy = 0.0;
  for (int i = 0; i < NT - 1; ++i) {
    const double t = (double)ts[i], dt = (double)(ts[i + 1] - ts[i]);
    const double k1 = t - yy;
    const double k2 = (t + 0.5 * dt) - (yy + 0.5 * dt * k1);
    const double k3 = (t + 0.5 * dt) - (yy + 0.5 * dt * k2);
    const double k4 = (t + dt) - (yy + dt * k3);
    yy += dt / 6.0 * (k1 + 2.0 * k2 + 2.0 * k3 + k4);
  }
  const float S = (float)yy;

  unsigned short* Wt = (unsigned short*)d_ws;                 // 2 MB bf16 W^T
  unsigned short* xb = Wt + (size_t)H * H;                    // 32 MB bf16 x
  unsigned short* g  = xb + (size_t)M * H;                    // 32 MB bf16 g
  const size_t needW  = (size_t)H * H * 2;
  const size_t needXb = (size_t)M * H * 2;
  const int n4 = M * H / 4;

  const int nblk256 = (M / 256) * (H / 256);
  const bool shapeOK = (H % 256 == 0) && (M % 256 == 0) && (nblk256 % 8 == 0)
                    && ((H >> 5) >= 3);   // pipeline needs >= 3 K-steps

  if (ws_size >= needW + 2 * needXb && shapeOK) {
    prep_all<<<256 + 2048, 256, 0, stream>>>(W, x, b, c, d, Wt, xb, g, H, n4);
    gemm_256<<<nblk256, 512, 0, stream>>>(xb, Wt, g, out, S, H);
  } else if (ws_size >= needW + needXb) {
    dim3 tgrid(H / 64, H / 64);
    transpose_W<<<tgrid, 256, 0, stream>>>(W, Wt, H);
    cvt_x<<<2048, 256, 0, stream>>>(x, xb, n4);
    gemm_fb<1><<<(H / 128) * (M / 128), 256, 0, stream>>>(x, xb, Wt, b, c, d, out, S, H);
  } else {
    dim3 tgrid(H / 64, H / 64);
    transpose_W<<<tgrid, 256, 0, stream>>>(W, Wt, H);
    gemm_fb<2><<<(H / 128) * (M / 128), 256, 0, stream>>>(x, nullptr, Wt, b, c, d, out, S, H);
  }
}

// Round 16
// 80.209 us; speedup vs baseline: 1.0142x; 1.0142x over previous
//
#include <hip/hip_runtime.h>
#include <hip/hip_bf16.h>

typedef __attribute__((ext_vector_type(4))) float  f32x4;
typedef __attribute__((ext_vector_type(8))) short  bf16x8;
typedef __attribute__((ext_vector_type(4))) short  bf16x4v;

#define EPAD 68   // f32 elems per epilogue LDS row
#define AS1 __attribute__((address_space(1)))
#define AS3 __attribute__((address_space(3)))

__device__ __forceinline__ unsigned short f2bf(float f) {
  __hip_bfloat16 h = __float2bfloat16(f);
  unsigned short u; __builtin_memcpy(&u, &h, 2); return u;
}
__device__ __forceinline__ float bf2f(short u) {
  unsigned int w = ((unsigned int)(unsigned short)u) << 16;
  float f; __builtin_memcpy(&f, &w, 4); return f;
}

// Fully-inline sincos. k in f32 (|x|<=~6 -> k exact), reduction in f64
// (tan pole needs ABSOLUTE reduced-arg err < ~6e-9), polys f32.
__device__ __forceinline__ void my_sincos(float xf, float& s_out, float& c_out) {
  const float kf = __builtin_rintf(xf * 0.636619772367581343f);      // x * 2/pi
  const int   q  = (int)kf;
  const double kd = (double)kf;
  double rd = __builtin_fma(-kd, 1.5707963267948966,    (double)xf); // pio2_hi
  rd        = __builtin_fma(-kd, 6.123233995736766e-17, rd);         // pio2_lo
  const float r = (float)rd;
  const float z = r * r;
  const float ps = fmaf(z, fmaf(z, fmaf(z, 2.7183114939898219e-06f,
                                           -1.9839334836096632e-04f),
                                   8.3333293858894632e-03f),
                        -1.6666666641626524e-01f);
  const float sr = fmaf(r * z, ps, r);                               // sin(r)
  const float pc = fmaf(z, fmaf(z, fmaf(z, 2.4390448796277409e-05f,
                                           -1.3886763774609929e-03f),
                                   4.1666623323739063e-02f),
                        -4.9999999725103100e-01f);
  const float cr = fmaf(z, pc, 1.0f);                                // cos(r)
  const bool swap = (q & 1) != 0;
  float s1 = swap ? cr : sr;
  float c1 = swap ? sr : cr;
  if (q & 2)       s1 = -s1;
  if ((q + 1) & 2) c1 = -c1;
  s_out = s1; c_out = c1;
}

// ---- fused prep: blocks 0..255 transpose W -> Wt(bf16); blocks 256+ stream
// x -> xb(bf16) and g = b*sin(x)+c*cos(x)+d*tan(x) -> bf16 (trig hides under
// the memory-bound stream; measured at the BW floor ~22 us).
__global__ __launch_bounds__(256)
void prep_all(const float* __restrict__ W, const float* __restrict__ x,
              const float* __restrict__ bv, const float* __restrict__ cv,
              const float* __restrict__ dv,
              unsigned short* __restrict__ Wt, unsigned short* __restrict__ xb,
              unsigned short* __restrict__ g, int H, int n4) {
  __shared__ float tile[64][65];
  const int t = threadIdx.x;
  if (blockIdx.x < 256) {
    const int blk = blockIdx.x;
    const int n0 = (blk & 15) << 6;
    const int k0 = (blk >> 4) << 6;
    #pragma unroll
    for (int it = 0; it < 4; ++it) {
      int q = it * 256 + t;
      int r = q >> 4, c4 = (q & 15) << 2;
      f32x4 v = *(const f32x4*)&W[(size_t)(k0 + r) * H + n0 + c4];
      tile[r][c4 + 0] = v[0]; tile[r][c4 + 1] = v[1];
      tile[r][c4 + 2] = v[2]; tile[r][c4 + 3] = v[3];
    }
    __syncthreads();
    #pragma unroll
    for (int it = 0; it < 4; ++it) {
      int q = it * 256 + t;
      int r = q >> 4, c4 = (q & 15) << 2;
      bf16x4v o;
      #pragma unroll
      for (int j = 0; j < 4; ++j) o[j] = (short)f2bf(tile[c4 + j][r]);
      *(bf16x4v*)&Wt[(size_t)(n0 + r) * H + k0 + c4] = o;
    }
  } else {
    const int jm = (H >> 2) - 1;             // H pow2: chunk-index mask
    int i = (blockIdx.x - 256) * 256 + t;
    const int stride = ((int)gridDim.x - 256) * 256;
    for (; i < n4; i += stride) {
      f32x4 v = ((const f32x4*)x)[i];
      const int j4 = (i & jm) << 2;
      f32x4 b4 = *(const f32x4*)&bv[j4];
      f32x4 c4 = *(const f32x4*)&cv[j4];
      f32x4 d4 = *(const f32x4*)&dv[j4];
      bf16x4v xo, go;
      #pragma unroll
      for (int e = 0; e < 4; ++e) {
        xo[e] = (short)f2bf(v[e]);
        float s, co;
        my_sincos(v[e], s, co);
        const float tn = s * __builtin_amdgcn_rcpf(co);  // |err| ~0.13 @ pole
        go[e] = (short)f2bf(fmaf(b4[e], s, fmaf(c4[e], co, d4[e] * tn)));
      }
      ((bf16x4v*)xb)[i] = xo;
      ((bf16x4v*)g)[i]  = go;
    }
  }
}

// ---- fallback prep kernels ----
__global__ __launch_bounds__(256)
void transpose_W(const float* __restrict__ W, unsigned short* __restrict__ Wt, int H) {
  __shared__ float tile[64][65];
  const int k0 = blockIdx.y * 64;
  const int n0 = blockIdx.x * 64;
  const int t = threadIdx.x;
  #pragma unroll
  for (int it = 0; it < 4; ++it) {
    int q = it * 256 + t;
    int r = q >> 4, c4 = (q & 15) << 2;
    f32x4 v = *(const f32x4*)&W[(size_t)(k0 + r) * H + n0 + c4];
    tile[r][c4 + 0] = v[0]; tile[r][c4 + 1] = v[1];
    tile[r][c4 + 2] = v[2]; tile[r][c4 + 3] = v[3];
  }
  __syncthreads();
  #pragma unroll
  for (int it = 0; it < 4; ++it) {
    int q = it * 256 + t;
    int r = q >> 4, c4 = (q & 15) << 2;
    bf16x4v o;
    #pragma unroll
    for (int j = 0; j < 4; ++j) o[j] = (short)f2bf(tile[c4 + j][r]);
    *(bf16x4v*)&Wt[(size_t)(n0 + r) * H + k0 + c4] = o;
  }
}
__global__ __launch_bounds__(256)
void cvt_x(const float* __restrict__ x, unsigned short* __restrict__ xb, int n4) {
  int i = blockIdx.x * 256 + threadIdx.x;
  const int stride = gridDim.x * 256;
  for (; i < n4; i += stride) {
    f32x4 v = ((const f32x4*)x)[i];
    bf16x4v o;
    #pragma unroll
    for (int j = 0; j < 4; ++j) o[j] = (short)f2bf(v[j]);
    ((bf16x4v*)xb)[i] = o;
  }
}

// ---- main GEMM: 256x128 tile, 8 waves, r13 schedule, 2 blocks/CU ----
// r15 diagnosis: all sync variants converge to 58us because the 256^2 grid
// is exactly 256 blocks = 1/CU -- no TLP to hide per-phase latency chains,
// and the terminal epilogue burst runs with the matrix pipe idle. Fix: halve
// BN -> grid 512 = 2 co-resident blocks/CU (LDS 48KB/block, launch_bounds
// (512,4) = 4 waves/EU = 2 blocks/CU). Per-SIMD MFMA density is unchanged
// (4 waves x 16 MFMA/step), but the CU now has two INDEPENDENT sync domains:
// one block's barrier/vmcnt stall and epilogue backfill with the other's
// K-loop. Schedule is r13's proven dbuf (STAGE(t+1) -> compute(t) ->
// __syncthreads), swizzle maps re-derived for 256x128 (same bijection).
// Slot: A [256][32]sw 16KB @ +0, B [128][32]sw 8KB @ +16384; 2 slots.
__global__ __launch_bounds__(512, 4)
void gemm_256(const unsigned short* __restrict__ xb,
              const unsigned short* __restrict__ Wt,
              const unsigned short* __restrict__ g,
              float* __restrict__ out, float S, int H) {
  __shared__ unsigned char smem[49152];             // 2 x 24KB K-tile slots
  float* Es = (float*)smem;                         // epilogue overlay (34.8KB)

  const int tid  = threadIdx.x;
  const int nwg  = gridDim.x;
  const int work = (blockIdx.x & 7) * (nwg >> 3) + (blockIdx.x >> 3);
  const int nbj  = H >> 7;                          // N tiles of 128
  const int bj   = work % nbj;
  const int bi   = work / nbj;
  const int i0   = bi * 256, j0 = bj * 128;
  const int wave = tid >> 6, lane = tid & 63;
  const int wr   = wave >> 1, wc = wave & 1;        // 4(M) x 2(N) wave grid
  const int l16  = lane & 15, lq = lane >> 4;

  // Staging sources (inverse swizzle; r10-verified bijection).
  // A region (16KB): issues at D = {tid*16, 8192+tid*16}; B region (8KB):
  // one issue at D = tid*16. sup=D>>7; slotL=((D>>4)&7)^(sup&7);
  // row=sup*2+(slotL>>2); col=(slotL&3)*8.
  const unsigned short *aS0, *aS1, *bS0;
  {
    const int D0 = tid * 16,        sup0 = D0 >> 7;
    const int sl0 = ((D0 >> 4) & 7) ^ (sup0 & 7);
    const int r0  = sup0 * 2 + (sl0 >> 2), c0 = (sl0 & 3) << 3;
    const int D1 = 8192 + tid * 16, sup1 = D1 >> 7;
    const int sl1 = ((D1 >> 4) & 7) ^ (sup1 & 7);
    const int r1  = sup1 * 2 + (sl1 >> 2), c1 = (sl1 & 3) << 3;
    aS0 = &xb[(size_t)(i0 + r0) * H + c0];
    aS1 = &xb[(size_t)(i0 + r1) * H + c1];
    bS0 = &Wt[(size_t)(j0 + r0) * H + c0];          // B rows 0..127 via D0 map
  }

  #define STAGE(bufsel, kOff)                                                   \
    do {                                                                        \
      char* _b = (char*)smem + (bufsel) * 24576;                                \
      __builtin_amdgcn_global_load_lds((const AS1 void*)(aS0 + (kOff)),         \
        (AS3 void*)(_b + tid * 16), 16, 0, 0);                                  \
      __builtin_amdgcn_global_load_lds((const AS1 void*)(aS1 + (kOff)),         \
        (AS3 void*)(_b + 8192 + tid * 16), 16, 0, 0);                           \
      __builtin_amdgcn_global_load_lds((const AS1 void*)(bS0 + (kOff)),         \
        (AS3 void*)(_b + 16384 + tid * 16), 16, 0, 0);                          \
    } while (0)

  // Fragment read offsets (forward swizzle; r10-verified conflict-free).
  // A logical row R = wr*64 + mi*16 + l16 -> byte (R>>1)*128 + slot*16;
  // (R>>1)&7 = (l16>>1)&7 (wr*32, mi*8 vanish mod 8) -> aBase = wr*4096+laneT.
  const int slotx = (4 * (l16 & 1) + lq) ^ ((l16 >> 1) & 7);
  const int laneT = (l16 >> 1) * 128 + slotx * 16;
  const int aBase = wr * 4096 + laneT;              // + mi*1024
  const int bBase = wc * 4096 + laneT;              // + ni*1024

  f32x4 acc[4][4] = {};

  const int nsteps = H >> 5;                        // BK = 32
  STAGE(0, 0);
  __syncthreads();                                  // prologue DMA landed
  for (int t = 0; t < nsteps; ++t) {
    if (t + 1 < nsteps) STAGE((t + 1) & 1, (t + 1) * 32);
    const char* Ab = (const char*)smem + (t & 1) * 24576;
    const char* Bb = Ab + 16384;
    bf16x8 bfr[4];
    #pragma unroll
    for (int ni = 0; ni < 4; ++ni)
      bfr[ni] = *(const bf16x8*)(Bb + bBase + ni * 1024);
    #pragma unroll
    for (int mi = 0; mi < 4; ++mi) {
      bf16x8 af = *(const bf16x8*)(Ab + aBase + mi * 1024);
      #pragma unroll
      for (int ni = 0; ni < 4; ++ni)
        acc[mi][ni] = __builtin_amdgcn_mfma_f32_16x16x32_bf16(af, bfr[ni], acc[mi][ni], 0, 0, 0);
    }
    __syncthreads();   // vmcnt(0)+barrier: tile t+1 landed, buf t released
  }
  #undef STAGE

  // ---- epilogue: per-wave LDS transpose then coalesced f32x4 IO ----
  // C/D fragment layout: col = l16, row = lq*4 + r  [m89-verified]
  float* ep = Es + wave * (16 * EPAD);
  const int rr = lane >> 2;           // 0..15
  const int cq = (lane & 3) * 16;     // 0,16,32,48
  #pragma unroll
  for (int mi = 0; mi < 4; ++mi) {
    #pragma unroll
    for (int ni = 0; ni < 4; ++ni)
      #pragma unroll
      for (int r = 0; r < 4; ++r)
        ep[(lq * 4 + r) * EPAD + ni * 16 + l16] = acc[mi][ni][r];
    // same-wave ds_write -> ds_read: in-order LDS pipe, compiler waits lgkmcnt.
    const int i  = i0 + wr * 64 + mi * 16 + rr;
    const int jb = j0 + wc * 64 + cq;
    float* orow = &out[(size_t)i * H + jb];
    const unsigned short* grow = &g[(size_t)i * H + jb];
    #pragma unroll
    for (int t = 0; t < 4; ++t) {
      f32x4 a = *(const f32x4*)&ep[rr * EPAD + cq + 4 * t];
      bf16x4v gv = *(const bf16x4v*)&grow[4 * t];
      f32x4 o;
      #pragma unroll
      for (int e = 0; e < 4; ++e) o[e] = S * (a[e] + bf2f(gv[e]));
      *(f32x4*)&orow[4 * t] = o;
    }
  }
}

// ---- fallback GEMM (round-6 structure, 256 thr) for small-ws / odd-shape ----
template <int MODE>   // 1: xb staging + trig epi ; 2: f32 staging + trig epi
__global__ __launch_bounds__(256, 2)
void gemm_fb(const float* __restrict__ x, const unsigned short* __restrict__ xb,
             const unsigned short* __restrict__ Wt,
             const float* __restrict__ bv, const float* __restrict__ cv,
             const float* __restrict__ dv, float* __restrict__ out,
             float S, int H) {
  __shared__ unsigned char smem[36864];
  unsigned short* As = (unsigned short*)smem;            // [128][72]
  unsigned short* Bs = As + 128 * 72;
  float*          Es = (float*)smem;

  const int tid  = threadIdx.x;
  const int nwg  = gridDim.x;
  const int work = (nwg % 8 == 0) ? (blockIdx.x & 7) * (nwg >> 3) + (blockIdx.x >> 3)
                                  : blockIdx.x;
  const int nbj  = H / 128;
  const int bj   = work % nbj;
  const int bi   = work / nbj;
  const int i0   = bi * 128, j0 = bj * 128;
  const int wave = tid >> 6, lane = tid & 63;
  const int wr = wave >> 1, wc = wave & 1;
  const int l16 = lane & 15, lq = lane >> 4;

  f32x4 acc[4][4] = {};
  for (int kk = 0; kk < H; kk += 64) {
    if constexpr (MODE == 1) {
      #pragma unroll
      for (int it = 0; it < 4; ++it) {
        int q = it * 256 + tid;
        int r = q >> 3, c8 = (q & 7) << 3;
        *(bf16x8*)&As[r * 72 + c8] = *(const bf16x8*)&xb[(size_t)(i0 + r) * H + kk + c8];
      }
    } else {
      #pragma unroll
      for (int it = 0; it < 8; ++it) {
        int q = it * 256 + tid;
        int r = q >> 4, c4 = (q & 15) << 2;
        f32x4 v = *(const f32x4*)&x[(size_t)(i0 + r) * H + kk + c4];
        bf16x4v o;
        #pragma unroll
        for (int j = 0; j < 4; ++j) o[j] = (short)f2bf(v[j]);
        *(bf16x4v*)&As[r * 72 + c4] = o;
      }
    }
    #pragma unroll
    for (int it = 0; it < 4; ++it) {
      int q = it * 256 + tid;
      int r = q >> 3, c8 = (q & 7) << 3;
      *(bf16x8*)&Bs[r * 72 + c8] = *(const bf16x8*)&Wt[(size_t)(j0 + r) * H + kk + c8];
    }
    __syncthreads();
    #pragma unroll
    for (int s = 0; s < 2; ++s) {
      bf16x8 af[4], bfr[4];
      #pragma unroll
      for (int mi = 0; mi < 4; ++mi)
        af[mi] = *(const bf16x8*)&As[(wr * 64 + mi * 16 + l16) * 72 + s * 32 + lq * 8];
      #pragma unroll
      for (int ni = 0; ni < 4; ++ni)
        bfr[ni] = *(const bf16x8*)&Bs[(wc * 64 + ni * 16 + l16) * 72 + s * 32 + lq * 8];
      #pragma unroll
      for (int mi = 0; mi < 4; ++mi)
        #pragma unroll
        for (int ni = 0; ni < 4; ++ni)
          acc[mi][ni] = __builtin_amdgcn_mfma_f32_16x16x32_bf16(af[mi], bfr[ni], acc[mi][ni], 0, 0, 0);
    }
    __syncthreads();
  }
  float* ep = Es + wave * (16 * EPAD);
  const int rr = lane >> 2;
  const int cq = (lane & 3) * 16;
  #pragma unroll
  for (int mi = 0; mi < 4; ++mi) {
    #pragma unroll
    for (int ni = 0; ni < 4; ++ni)
      #pragma unroll
      for (int r = 0; r < 4; ++r)
        ep[(lq * 4 + r) * EPAD + ni * 16 + l16] = acc[mi][ni][r];
    const int i  = i0 + wr * 64 + mi * 16 + rr;
    const int jb = j0 + wc * 64 + cq;
    const float* xrow = &x[(size_t)i * H + jb];
    float*       orow = &out[(size_t)i * H + jb];
    #pragma unroll
    for (int t = 0; t < 4; ++t) {
      f32x4 a  = *(const f32x4*)&ep[rr * EPAD + cq + 4 * t];
      f32x4 xv = *(const f32x4*)&xrow[4 * t];
      f32x4 b4 = *(const f32x4*)&bv[jb + 4 * t];
      f32x4 c4 = *(const f32x4*)&cv[jb + 4 * t];
      f32x4 d4 = *(const f32x4*)&dv[jb + 4 * t];
      f32x4 o;
      #pragma unroll
      for (int e = 0; e < 4; ++e) {
        float s, co;
        my_sincos(xv[e], s, co);
        const float tanv = s * __builtin_amdgcn_rcpf(co);
        o[e] = S * (fmaf(b4[e], s, a[e]) + fmaf(c4[e], co, d4[e] * tanv));
      }
      *(f32x4*)&orow[4 * t] = o;
    }
  }
}

extern "C" void kernel_launch(void* const* d_in, const int* in_sizes, int n_in,
                              void* d_out, int out_size, void* d_ws, size_t ws_size,
                              hipStream_t stream) {
  const float* x = (const float*)d_in[0];
  const float* W = (const float*)d_in[1];
  const float* b = (const float*)d_in[2];
  const float* c = (const float*)d_in[3];
  const float* d = (const float*)d_in[4];
  float* out = (float*)d_out;
  const int H = in_sizes[2];          // 1024
  const int M = in_sizes[0] / H;      // 16384

  // Scalar RK4 factor: y_final = S * z (ODE linear in y, y0 = 0).
  const int NT = 100;
  float ts[NT];
  const float step = (float)(1.0 / 99.0);
  for (int i = 0; i < NT; ++i) ts[i] = (float)i * step;
  ts[NT - 1] = 1.0f;
  double yy = 0.0;
  for (int i = 0; i < NT - 1; ++i) {
    const double t = (double)ts[i], dt = (double)(ts[i + 1] - ts[i]);
    const double k1 = t - yy;
    const double k2 = (t + 0.5 * dt) - (yy + 0.5 * dt * k1);
    const double k3 = (t + 0.5 * dt) - (yy + 0.5 * dt * k2);
    const double k4 = (t + dt) - (yy + dt * k3);
    yy += dt / 6.0 * (k1 + 2.0 * k2 + 2.0 * k3 + k4);
  }
  const float S = (float)yy;

  unsigned short* Wt = (unsigned short*)d_ws;                 // 2 MB bf16 W^T
  unsigned short* xb = Wt + (size_t)H * H;                    // 32 MB bf16 x
  unsigned short* g  = xb + (size_t)M * H;                    // 32 MB bf16 g
  const size_t needW  = (size_t)H * H * 2;
  const size_t needXb = (size_t)M * H * 2;
  const int n4 = M * H / 4;

  const int nblk = (M / 256) * (H / 128);                     // 512
  const bool shapeOK = (H % 128 == 0) && (M % 256 == 0) && (nblk % 8 == 0)
                    && ((H >> 5) >= 2);

  if (ws_size >= needW + 2 * needXb && shapeOK) {
    prep_all<<<256 + 2048, 256, 0, stream>>>(W, x, b, c, d, Wt, xb, g, H, n4);
    gemm_256<<<nblk, 512, 0, stream>>>(xb, Wt, g, out, S, H);
  } else if (ws_size >= needW + needXb) {
    dim3 tgrid(H / 64, H / 64);
    transpose_W<<<tgrid, 256, 0, stream>>>(W, Wt, H);
    cvt_x<<<2048, 256, 0, stream>>>(x, xb, n4);
    gemm_fb<1><<<(H / 128) * (M / 128), 256, 0, stream>>>(x, xb, Wt, b, c, d, out, S, H);
  } else {
    dim3 tgrid(H / 64, H / 64);
    transpose_W<<<tgrid, 256, 0, stream>>>(W, Wt, H);
    gemm_fb<2><<<(H / 128) * (M / 128), 256, 0, stream>>>(x, nullptr, Wt, b, c, d, out, S, H);
  }
}

// Round 17
// 76.354 us; speedup vs baseline: 1.0654x; 1.0505x over previous
//
#include <hip/hip_runtime.h>
#include <hip/hip_bf16.h>

typedef __attribute__((ext_vector_type(4))) float  f32x4;
typedef __attribute__((ext_vector_type(8))) short  bf16x8;
typedef __attribute__((ext_vector_type(4))) short  bf16x4v;

#define EPAD 68   // f32 elems per epilogue LDS row

__device__ __forceinline__ unsigned short f2bf(float f) {
  __hip_bfloat16 h = __float2bfloat16(f);
  unsigned short u; __builtin_memcpy(&u, &h, 2); return u;
}

// Fully-inline sincos. k in f32 (|x|<=~6 -> k exact), reduction in f64
// (tan pole needs ABSOLUTE reduced-arg err < ~6e-9), polys f32.
__device__ __forceinline__ void my_sincos(float xf, float& s_out, float& c_out) {
  const float kf = __builtin_rintf(xf * 0.636619772367581343f);      // x * 2/pi
  const int   q  = (int)kf;
  const double kd = (double)kf;
  double rd = __builtin_fma(-kd, 1.5707963267948966,    (double)xf); // pio2_hi
  rd        = __builtin_fma(-kd, 6.123233995736766e-17, rd);         // pio2_lo
  const float r = (float)rd;
  const float z = r * r;
  const float ps = fmaf(z, fmaf(z, fmaf(z, 2.7183114939898219e-06f,
                                           -1.9839334836096632e-04f),
                                   8.3333293858894632e-03f),
                        -1.6666666641626524e-01f);
  const float sr = fmaf(r * z, ps, r);                               // sin(r)
  const float pc = fmaf(z, fmaf(z, fmaf(z, 2.4390448796277409e-05f,
                                           -1.3886763774609929e-03f),
                                   4.1666623323739063e-02f),
                        -4.9999999725103100e-01f);
  const float cr = fmaf(z, pc, 1.0f);                                // cos(r)
  const bool swap = (q & 1) != 0;
  float s1 = swap ? cr : sr;
  float c1 = swap ? sr : cr;
  if (q & 2)       s1 = -s1;
  if ((q + 1) & 2) c1 = -c1;
  s_out = s1; c_out = c1;
}

// forward LDS swizzle (r10/r16-verified bijection, conflict-free reads):
// slot (row r, 16B-chunk c in 0..3) -> byte (r>>1)*128 + ((4*(r&1)+c)^((r>>1)&7))*16
__device__ __forceinline__ int swz(int r, int c) {
  return (r >> 1) * 128 + (((4 * (r & 1) + c) ^ ((r >> 1) & 7)) << 4);
}

// ---- prep: W (H,H) f32 row-major -> Wt (H,H) bf16 transposed (~3 us) ----
__global__ __launch_bounds__(256)
void transpose_W(const float* __restrict__ W, unsigned short* __restrict__ Wt, int H) {
  __shared__ float tile[64][65];
  const int k0 = blockIdx.y * 64;
  const int n0 = blockIdx.x * 64;
  const int t = threadIdx.x;
  #pragma unroll
  for (int it = 0; it < 4; ++it) {
    int q = it * 256 + t;
    int r = q >> 4, c4 = (q & 15) << 2;
    f32x4 v = *(const f32x4*)&W[(size_t)(k0 + r) * H + n0 + c4];
    tile[r][c4 + 0] = v[0]; tile[r][c4 + 1] = v[1];
    tile[r][c4 + 2] = v[2]; tile[r][c4 + 3] = v[3];
  }
  __syncthreads();
  #pragma unroll
  for (int it = 0; it < 4; ++it) {
    int q = it * 256 + t;
    int r = q >> 4, c4 = (q & 15) << 2;
    bf16x4v o;
    #pragma unroll
    for (int j = 0; j < 4; ++j) o[j] = (short)f2bf(tile[c4 + j][r]);
    *(bf16x4v*)&Wt[(size_t)(n0 + r) * H + k0 + c4] = o;
  }
}

// ---- fully-fused GEMM: 256x128 tile, 8 waves, 2 blocks/CU ----
// r17: the 22us prep pass (xb+g production, 134MB of streaming) is folded
// into the gemm, which had idle VALU (15%) and BW (24%):
//  - A staged DIRECTLY from f32 x with in-register f32->bf16 convert
//    (r6-proven), written with the FORWARD swizzle via ds_write_b128
//    (reg-staging has no linear-dest constraint -- rule #21 satisfied
//    trivially: swizzle on write AND read).
//  - trig computed in the epilogue from f32 x (r7-proven; rows L2-hot
//    from staging). No xb, no g, no prep stream.
// Schedule: BK=64 single-buffer, 2 barriers/step (r6's compiler-hoisted
// variant -- LLVM pipelines the __restrict f32 loads into the MFMA phase).
// LDS slot: A [2 halves][256][32]sw = 32KB @0, B [2][128][32]sw = 16KB @32K.
// 48KB + launch_bounds(512,4) -> 2 blocks/CU (r16's TLP win preserved).
__global__ __launch_bounds__(512, 4)
void gemm_fused256(const float* __restrict__ x,
                   const unsigned short* __restrict__ Wt,
                   const float* __restrict__ bv, const float* __restrict__ cv,
                   const float* __restrict__ dv,
                   float* __restrict__ out, float S, int H) {
  __shared__ unsigned char smem[49152];
  float* Es = (float*)smem;                         // epilogue overlay (34.8KB)

  const int tid  = threadIdx.x;
  const int nwg  = gridDim.x;
  const int work = (blockIdx.x & 7) * (nwg >> 3) + (blockIdx.x >> 3);
  const int nbj  = H >> 7;                          // N tiles of 128
  const int bj   = work % nbj;
  const int bi   = work / nbj;
  const int i0   = bi * 256, j0 = bj * 128;
  const int wave = tid >> 6, lane = tid & 63;
  const int wr   = wave >> 1, wc = wave & 1;        // 4(M) x 2(N) wave grid
  const int l16  = lane & 15, lq = lane >> 4;

  // ---- staging maps (per K-half of 32 cols) ----
  // A half: 1024 slots of 16B (8 bf16): slot q -> r=q>>2, c=q&3.
  //   thread handles q = tid and q = tid+512.
  const int qa0 = tid,        ra0 = qa0 >> 2, ca0 = (qa0 & 3) << 3;
  const int qa1 = tid + 512,  ra1 = qa1 >> 2, ca1 = (qa1 & 3) << 3;
  const int pa0 = swz(ra0, qa0 & 3);
  const int pa1 = swz(ra1, qa1 & 3);
  // B half: 512 slots: q = tid -> r=tid>>2, c=tid&3.
  const int rb  = tid >> 2,   cbo = (tid & 3) << 3;
  const int pb  = swz(rb, tid & 3);

  const float*          aP0 = &x[(size_t)(i0 + ra0) * H + ca0];
  const float*          aP1 = &x[(size_t)(i0 + ra1) * H + ca1];
  const unsigned short* bP  = &Wt[(size_t)(j0 + rb) * H + cbo];

  // ---- fragment read bases (forward swizzle, r16-verified) ----
  const int slotx = (4 * (l16 & 1) + lq) ^ ((l16 >> 1) & 7);
  const int laneT = (l16 >> 1) * 128 + slotx * 16;
  const int aBase = wr * 4096 + laneT;              // + mi*1024, + half*16384
  const int bBase = wc * 4096 + laneT;              // + ni*1024, + 32768 + half*8192

  f32x4 acc[4][4] = {};

  for (int kk = 0; kk < H; kk += 64) {
    // ---- stage: A (f32 -> bf16 convert) + B (bf16 copy), both halves ----
    #pragma unroll
    for (int s = 0; s < 2; ++s) {
      const int ko = kk + s * 32;
      {
        f32x4 v0 = *(const f32x4*)(aP0 + ko);
        f32x4 v1 = *(const f32x4*)(aP0 + ko + 4);
        bf16x8 o;
        #pragma unroll
        for (int e = 0; e < 4; ++e) { o[e] = (short)f2bf(v0[e]); o[e + 4] = (short)f2bf(v1[e]); }
        *(bf16x8*)((char*)smem + s * 16384 + pa0) = o;
      }
      {
        f32x4 v0 = *(const f32x4*)(aP1 + ko);
        f32x4 v1 = *(const f32x4*)(aP1 + ko + 4);
        bf16x8 o;
        #pragma unroll
        for (int e = 0; e < 4; ++e) { o[e] = (short)f2bf(v0[e]); o[e + 4] = (short)f2bf(v1[e]); }
        *(bf16x8*)((char*)smem + s * 16384 + pa1) = o;
      }
      {
        bf16x8 w = *(const bf16x8*)(bP + ko);
        *(bf16x8*)((char*)smem + 32768 + s * 8192 + pb) = w;
      }
    }
    __syncthreads();
    // ---- compute: 2 K-subtiles x 16 fragments ----
    #pragma unroll
    for (int s = 0; s < 2; ++s) {
      const char* Ab = (const char*)smem + s * 16384;
      const char* Bb = (const char*)smem + 32768 + s * 8192;
      bf16x8 bfr[4];
      #pragma unroll
      for (int ni = 0; ni < 4; ++ni)
        bfr[ni] = *(const bf16x8*)(Bb + bBase + ni * 1024);
      #pragma unroll
      for (int mi = 0; mi < 4; ++mi) {
        bf16x8 af = *(const bf16x8*)(Ab + aBase + mi * 1024);
        #pragma unroll
        for (int ni = 0; ni < 4; ++ni)
          acc[mi][ni] = __builtin_amdgcn_mfma_f32_16x16x32_bf16(af, bfr[ni], acc[mi][ni], 0, 0, 0);
      }
    }
    __syncthreads();
  }

  // ---- epilogue: per-wave LDS transpose, coalesced f32x4 IO, inline trig ----
  // C/D fragment layout: col = l16, row = lq*4 + r  [m89-verified]
  float* ep = Es + wave * (16 * EPAD);
  const int rr = lane >> 2;           // 0..15
  const int cq = (lane & 3) * 16;     // 0,16,32,48
  #pragma unroll
  for (int mi = 0; mi < 4; ++mi) {
    #pragma unroll
    for (int ni = 0; ni < 4; ++ni)
      #pragma unroll
      for (int r = 0; r < 4; ++r)
        ep[(lq * 4 + r) * EPAD + ni * 16 + l16] = acc[mi][ni][r];
    // same-wave ds_write -> ds_read: in-order LDS pipe, compiler waits lgkmcnt.
    const int i  = i0 + wr * 64 + mi * 16 + rr;
    const int jb = j0 + wc * 64 + cq;
    const float* xrow = &x[(size_t)i * H + jb];
    float*       orow = &out[(size_t)i * H + jb];
    #pragma unroll
    for (int t = 0; t < 4; ++t) {
      f32x4 a  = *(const f32x4*)&ep[rr * EPAD + cq + 4 * t];
      f32x4 xv = *(const f32x4*)&xrow[4 * t];
      f32x4 b4 = *(const f32x4*)&bv[jb + 4 * t];
      f32x4 c4 = *(const f32x4*)&cv[jb + 4 * t];
      f32x4 d4 = *(const f32x4*)&dv[jb + 4 * t];
      f32x4 o;
      #pragma unroll
      for (int e = 0; e < 4; ++e) {
        float s, co;
        my_sincos(xv[e], s, co);
        const float tanv = s * __builtin_amdgcn_rcpf(co);  // 1e-7 rel; safe vs thr
        o[e] = S * (fmaf(b4[e], s, a[e]) + fmaf(c4[e], co, d4[e] * tanv));
      }
      *(f32x4*)&orow[4 * t] = o;
    }
  }
}

// ---- fallback GEMM (round-6 structure, 256 thr) for odd shapes ----
__global__ __launch_bounds__(256, 2)
void gemm_fb(const float* __restrict__ x, const unsigned short* __restrict__ Wt,
             const float* __restrict__ bv, const float* __restrict__ cv,
             const float* __restrict__ dv, float* __restrict__ out,
             float S, int H) {
  __shared__ unsigned char smem[36864];
  unsigned short* As = (unsigned short*)smem;            // [128][72]
  unsigned short* Bs = As + 128 * 72;
  float*          Es = (float*)smem;

  const int tid  = threadIdx.x;
  const int nwg  = gridDim.x;
  const int work = (nwg % 8 == 0) ? (blockIdx.x & 7) * (nwg >> 3) + (blockIdx.x >> 3)
                                  : blockIdx.x;
  const int nbj  = H / 128;
  const int bj   = work % nbj;
  const int bi   = work / nbj;
  const int i0   = bi * 128, j0 = bj * 128;
  const int wave = tid >> 6, lane = tid & 63;
  const int wr = wave >> 1, wc = wave & 1;
  const int l16 = lane & 15, lq = lane >> 4;

  f32x4 acc[4][4] = {};
  for (int kk = 0; kk < H; kk += 64) {
    #pragma unroll
    for (int it = 0; it < 8; ++it) {
      int q = it * 256 + tid;
      int r = q >> 4, c4 = (q & 15) << 2;
      f32x4 v = *(const f32x4*)&x[(size_t)(i0 + r) * H + kk + c4];
      bf16x4v o;
      #pragma unroll
      for (int j = 0; j < 4; ++j) o[j] = (short)f2bf(v[j]);
      *(bf16x4v*)&As[r * 72 + c4] = o;
    }
    #pragma unroll
    for (int it = 0; it < 4; ++it) {
      int q = it * 256 + tid;
      int r = q >> 3, c8 = (q & 7) << 3;
      *(bf16x8*)&Bs[r * 72 + c8] = *(const bf16x8*)&Wt[(size_t)(j0 + r) * H + kk + c8];
    }
    __syncthreads();
    #pragma unroll
    for (int s = 0; s < 2; ++s) {
      bf16x8 af[4], bfr[4];
      #pragma unroll
      for (int mi = 0; mi < 4; ++mi)
        af[mi] = *(const bf16x8*)&As[(wr * 64 + mi * 16 + l16) * 72 + s * 32 + lq * 8];
      #pragma unroll
      for (int ni = 0; ni < 4; ++ni)
        bfr[ni] = *(const bf16x8*)&Bs[(wc * 64 + ni * 16 + l16) * 72 + s * 32 + lq * 8];
      #pragma unroll
      for (int mi = 0; mi < 4; ++mi)
        #pragma unroll
        for (int ni = 0; ni < 4; ++ni)
          acc[mi][ni] = __builtin_amdgcn_mfma_f32_16x16x32_bf16(af[mi], bfr[ni], acc[mi][ni], 0, 0, 0);
    }
    __syncthreads();
  }
  float* ep = Es + wave * (16 * EPAD);
  const int rr = lane >> 2;
  const int cq = (lane & 3) * 16;
  #pragma unroll
  for (int mi = 0; mi < 4; ++mi) {
    #pragma unroll
    for (int ni = 0; ni < 4; ++ni)
      #pragma unroll
      for (int r = 0; r < 4; ++r)
        ep[(lq * 4 + r) * EPAD + ni * 16 + l16] = acc[mi][ni][r];
    const int i  = i0 + wr * 64 + mi * 16 + rr;
    const int jb = j0 + wc * 64 + cq;
    const float* xrow = &x[(size_t)i * H + jb];
    float*       orow = &out[(size_t)i * H + jb];
    #pragma unroll
    for (int t = 0; t < 4; ++t) {
      f32x4 a  = *(const f32x4*)&ep[rr * EPAD + cq + 4 * t];
      f32x4 xv = *(const f32x4*)&xrow[4 * t];
      f32x4 b4 = *(const f32x4*)&bv[jb + 4 * t];
      f32x4 c4 = *(const f32x4*)&cv[jb + 4 * t];
      f32x4 d4 = *(const f32x4*)&dv[jb + 4 * t];
      f32x4 o;
      #pragma unroll
      for (int e = 0; e < 4; ++e) {
        float s, co;
        my_sincos(xv[e], s, co);
        const float tanv = s * __builtin_amdgcn_rcpf(co);
        o[e] = S * (fmaf(b4[e], s, a[e]) + fmaf(c4[e], co, d4[e] * tanv));
      }
      *(f32x4*)&orow[4 * t] = o;
    }
  }
}

extern "C" void kernel_launch(void* const* d_in, const int* in_sizes, int n_in,
                              void* d_out, int out_size, void* d_ws, size_t ws_size,
                              hipStream_t stream) {
  const float* x = (const float*)d_in[0];
  const float* W = (const float*)d_in[1];
  const float* b = (const float*)d_in[2];
  const float* c = (const float*)d_in[3];
  const float* d = (const float*)d_in[4];
  float* out = (float*)d_out;
  const int H = in_sizes[2];          // 1024
  const int M = in_sizes[0] / H;      // 16384

  // Scalar RK4 factor: y_final = S * z (ODE linear in y, y0 = 0).
  const int NT = 100;
  float ts[NT];
  const float step = (float)(1.0 / 99.0);
  for (int i = 0; i < NT; ++i) ts[i] = (float)i * step;
  ts[NT - 1] = 1.0f;
  double yy = 0.0;
  for (int i = 0; i < NT - 1; ++i) {
    const double t = (double)ts[i], dt = (double)(ts[i + 1] - ts[i]);
    const double k1 = t - yy;
    const double k2 = (t + 0.5 * dt) - (yy + 0.5 * dt * k1);
    const double k3 = (t + 0.5 * dt) - (yy + 0.5 * dt * k2);
    const double k4 = (t + dt) - (yy + dt * k3);
    yy += dt / 6.0 * (k1 + 2.0 * k2 + 2.0 * k3 + k4);
  }
  const float S = (float)yy;

  unsigned short* Wt = (unsigned short*)d_ws;                 // 2 MB bf16 W^T
  const int nblk = (M / 256) * (H / 128);                     // 512
  const bool shapeOK = (H % 128 == 0) && (M % 256 == 0) && (nblk % 8 == 0)
                    && (H % 64 == 0);

  dim3 tgrid(H / 64, H / 64);
  transpose_W<<<tgrid, 256, 0, stream>>>(W, Wt, H);

  if (shapeOK) {
    gemm_fused256<<<nblk, 512, 0, stream>>>(x, Wt, b, c, d, out, S, H);
  } else {
    gemm_fb<<<(H / 128) * (M / 128), 256, 0, stream>>>(x, Wt, b, c, d, out, S, H);
  }
}

// Round 18
// 76.188 us; speedup vs baseline: 1.0677x; 1.0022x over previous
//
#include <hip/hip_runtime.h>
#include <hip/hip_bf16.h>

typedef __attribute__((ext_vector_type(4))) float  f32x4;
typedef __attribute__((ext_vector_type(8))) short  bf16x8;
typedef __attribute__((ext_vector_type(4))) short  bf16x4v;

#define EPAD 68   // f32 elems per epilogue LDS row

__device__ __forceinline__ unsigned short f2bf(float f) {
  __hip_bfloat16 h = __float2bfloat16(f);
  unsigned short u; __builtin_memcpy(&u, &h, 2); return u;
}

// Fully-inline sincos. k in f32 (|x|<=~6 -> k exact), reduction in f64
// (tan pole needs ABSOLUTE reduced-arg err < ~6e-9), polys f32.
__device__ __forceinline__ void my_sincos(float xf, float& s_out, float& c_out) {
  const float kf = __builtin_rintf(xf * 0.636619772367581343f);      // x * 2/pi
  const int   q  = (int)kf;
  const double kd = (double)kf;
  double rd = __builtin_fma(-kd, 1.5707963267948966,    (double)xf); // pio2_hi
  rd        = __builtin_fma(-kd, 6.123233995736766e-17, rd);         // pio2_lo
  const float r = (float)rd;
  const float z = r * r;
  const float ps = fmaf(z, fmaf(z, fmaf(z, 2.7183114939898219e-06f,
                                           -1.9839334836096632e-04f),
                                   8.3333293858894632e-03f),
                        -1.6666666641626524e-01f);
  const float sr = fmaf(r * z, ps, r);                               // sin(r)
  const float pc = fmaf(z, fmaf(z, fmaf(z, 2.4390448796277409e-05f,
                                           -1.3886763774609929e-03f),
                                   4.1666623323739063e-02f),
                        -4.9999999725103100e-01f);
  const float cr = fmaf(z, pc, 1.0f);                                // cos(r)
  const bool swap = (q & 1) != 0;
  float s1 = swap ? cr : sr;
  float c1 = swap ? sr : cr;
  if (q & 2)       s1 = -s1;
  if ((q + 1) & 2) c1 = -c1;
  s_out = s1; c_out = c1;
}

// forward LDS swizzle (r10/r16-verified bijection, conflict-free reads):
// slot (row r, 16B-chunk c in 0..3) -> byte (r>>1)*128 + ((4*(r&1)+c)^((r>>1)&7))*16
__device__ __forceinline__ int swz(int r, int c) {
  return (r >> 1) * 128 + (((4 * (r & 1) + c) ^ ((r >> 1) & 7)) << 4);
}

// ---- prep: W (H,H) f32 row-major -> Wt (H,H) bf16 transposed (~3 us) ----
__global__ __launch_bounds__(256)
void transpose_W(const float* __restrict__ W, unsigned short* __restrict__ Wt, int H) {
  __shared__ float tile[64][65];
  const int k0 = blockIdx.y * 64;
  const int n0 = blockIdx.x * 64;
  const int t = threadIdx.x;
  #pragma unroll
  for (int it = 0; it < 4; ++it) {
    int q = it * 256 + t;
    int r = q >> 4, c4 = (q & 15) << 2;
    f32x4 v = *(const f32x4*)&W[(size_t)(k0 + r) * H + n0 + c4];
    tile[r][c4 + 0] = v[0]; tile[r][c4 + 1] = v[1];
    tile[r][c4 + 2] = v[2]; tile[r][c4 + 3] = v[3];
  }
  __syncthreads();
  #pragma unroll
  for (int it = 0; it < 4; ++it) {
    int q = it * 256 + t;
    int r = q >> 4, c4 = (q & 15) << 2;
    bf16x4v o;
    #pragma unroll
    for (int j = 0; j < 4; ++j) o[j] = (short)f2bf(tile[c4 + j][r]);
    *(bf16x4v*)&Wt[(size_t)(n0 + r) * H + k0 + c4] = o;
  }
}

// ---- fully-fused GEMM: 256x128 tile, 8 waves, 2 blocks/CU ----
// r17 structure (best measured: 76.35 us total): prep folded into the gemm
// (A staged from f32 x with in-register convert + forward-swizzled
// ds_write_b128; trig in the epilogue from f32 x). Single-buffer BK=64,
// 2 barriers/step, compiler-hoisted load pipeline (r3/r6 lesson).
// r18 adds T5 s_setprio around the MFMA cluster: 2 INDEPENDENT blocks/CU
// (no cross-block barriers) = the regime where setprio measured positive
// (m191); lockstep-GEMM null (m190) doesn't apply here.
__global__ __launch_bounds__(512, 4)
void gemm_fused256(const float* __restrict__ x,
                   const unsigned short* __restrict__ Wt,
                   const float* __restrict__ bv, const float* __restrict__ cv,
                   const float* __restrict__ dv,
                   float* __restrict__ out, float S, int H) {
  __shared__ unsigned char smem[49152];
  float* Es = (float*)smem;                         // epilogue overlay (34.8KB)

  const int tid  = threadIdx.x;
  const int nwg  = gridDim.x;
  const int work = (blockIdx.x & 7) * (nwg >> 3) + (blockIdx.x >> 3);
  const int nbj  = H >> 7;                          // N tiles of 128
  const int bj   = work % nbj;
  const int bi   = work / nbj;
  const int i0   = bi * 256, j0 = bj * 128;
  const int wave = tid >> 6, lane = tid & 63;
  const int wr   = wave >> 1, wc = wave & 1;        // 4(M) x 2(N) wave grid
  const int l16  = lane & 15, lq = lane >> 4;

  // ---- staging maps (per K-half of 32 cols) ----
  const int qa0 = tid,        ra0 = qa0 >> 2, ca0 = (qa0 & 3) << 3;
  const int qa1 = tid + 512,  ra1 = qa1 >> 2, ca1 = (qa1 & 3) << 3;
  const int pa0 = swz(ra0, qa0 & 3);
  const int pa1 = swz(ra1, qa1 & 3);
  const int rb  = tid >> 2,   cbo = (tid & 3) << 3;
  const int pb  = swz(rb, tid & 3);

  const float*          aP0 = &x[(size_t)(i0 + ra0) * H + ca0];
  const float*          aP1 = &x[(size_t)(i0 + ra1) * H + ca1];
  const unsigned short* bP  = &Wt[(size_t)(j0 + rb) * H + cbo];

  // ---- fragment read bases (forward swizzle, r16-verified) ----
  const int slotx = (4 * (l16 & 1) + lq) ^ ((l16 >> 1) & 7);
  const int laneT = (l16 >> 1) * 128 + slotx * 16;
  const int aBase = wr * 4096 + laneT;              // + mi*1024, + half*16384
  const int bBase = wc * 4096 + laneT;              // + ni*1024, + 32768 + half*8192

  f32x4 acc[4][4] = {};

  for (int kk = 0; kk < H; kk += 64) {
    // ---- stage: A (f32 -> bf16 convert) + B (bf16 copy), both halves ----
    #pragma unroll
    for (int s = 0; s < 2; ++s) {
      const int ko = kk + s * 32;
      {
        f32x4 v0 = *(const f32x4*)(aP0 + ko);
        f32x4 v1 = *(const f32x4*)(aP0 + ko + 4);
        bf16x8 o;
        #pragma unroll
        for (int e = 0; e < 4; ++e) { o[e] = (short)f2bf(v0[e]); o[e + 4] = (short)f2bf(v1[e]); }
        *(bf16x8*)((char*)smem + s * 16384 + pa0) = o;
      }
      {
        f32x4 v0 = *(const f32x4*)(aP1 + ko);
        f32x4 v1 = *(const f32x4*)(aP1 + ko + 4);
        bf16x8 o;
        #pragma unroll
        for (int e = 0; e < 4; ++e) { o[e] = (short)f2bf(v0[e]); o[e + 4] = (short)f2bf(v1[e]); }
        *(bf16x8*)((char*)smem + s * 16384 + pa1) = o;
      }
      {
        bf16x8 w = *(const bf16x8*)(bP + ko);
        *(bf16x8*)((char*)smem + 32768 + s * 8192 + pb) = w;
      }
    }
    __syncthreads();
    // ---- compute: 2 K-subtiles x 16 fragments, MFMA cluster at prio 1 ----
    __builtin_amdgcn_s_setprio(1);
    #pragma unroll
    for (int s = 0; s < 2; ++s) {
      const char* Ab = (const char*)smem + s * 16384;
      const char* Bb = (const char*)smem + 32768 + s * 8192;
      bf16x8 bfr[4];
      #pragma unroll
      for (int ni = 0; ni < 4; ++ni)
        bfr[ni] = *(const bf16x8*)(Bb + bBase + ni * 1024);
      #pragma unroll
      for (int mi = 0; mi < 4; ++mi) {
        bf16x8 af = *(const bf16x8*)(Ab + aBase + mi * 1024);
        #pragma unroll
        for (int ni = 0; ni < 4; ++ni)
          acc[mi][ni] = __builtin_amdgcn_mfma_f32_16x16x32_bf16(af, bfr[ni], acc[mi][ni], 0, 0, 0);
      }
    }
    __builtin_amdgcn_s_setprio(0);
    __syncthreads();
  }

  // ---- epilogue: per-wave LDS transpose, coalesced f32x4 IO, inline trig ----
  // C/D fragment layout: col = l16, row = lq*4 + r  [m89-verified]
  float* ep = Es + wave * (16 * EPAD);
  const int rr = lane >> 2;           // 0..15
  const int cq = (lane & 3) * 16;     // 0,16,32,48
  #pragma unroll
  for (int mi = 0; mi < 4; ++mi) {
    #pragma unroll
    for (int ni = 0; ni < 4; ++ni)
      #pragma unroll
      for (int r = 0; r < 4; ++r)
        ep[(lq * 4 + r) * EPAD + ni * 16 + l16] = acc[mi][ni][r];
    // same-wave ds_write -> ds_read: in-order LDS pipe, compiler waits lgkmcnt.
    const int i  = i0 + wr * 64 + mi * 16 + rr;
    const int jb = j0 + wc * 64 + cq;
    const float* xrow = &x[(size_t)i * H + jb];
    float*       orow = &out[(size_t)i * H + jb];
    #pragma unroll
    for (int t = 0; t < 4; ++t) {
      f32x4 a  = *(const f32x4*)&ep[rr * EPAD + cq + 4 * t];
      f32x4 xv = *(const f32x4*)&xrow[4 * t];
      f32x4 b4 = *(const f32x4*)&bv[jb + 4 * t];
      f32x4 c4 = *(const f32x4*)&cv[jb + 4 * t];
      f32x4 d4 = *(const f32x4*)&dv[jb + 4 * t];
      f32x4 o;
      #pragma unroll
      for (int e = 0; e < 4; ++e) {
        float s, co;
        my_sincos(xv[e], s, co);
        const float tanv = s * __builtin_amdgcn_rcpf(co);  // 1e-7 rel; safe vs thr
        o[e] = S * (fmaf(b4[e], s, a[e]) + fmaf(c4[e], co, d4[e] * tanv));
      }
      *(f32x4*)&orow[4 * t] = o;
    }
  }
}

// ---- fallback GEMM (round-6 structure, 256 thr) for odd shapes ----
__global__ __launch_bounds__(256, 2)
void gemm_fb(const float* __restrict__ x, const unsigned short* __restrict__ Wt,
             const float* __restrict__ bv, const float* __restrict__ cv,
             const float* __restrict__ dv, float* __restrict__ out,
             float S, int H) {
  __shared__ unsigned char smem[36864];
  unsigned short* As = (unsigned short*)smem;            // [128][72]
  unsigned short* Bs = As + 128 * 72;
  float*          Es = (float*)smem;

  const int tid  = threadIdx.x;
  const int nwg  = gridDim.x;
  const int work = (nwg % 8 == 0) ? (blockIdx.x & 7) * (nwg >> 3) + (blockIdx.x >> 3)
                                  : blockIdx.x;
  const int nbj  = H / 128;
  const int bj   = work % nbj;
  const int bi   = work / nbj;
  const int i0   = bi * 128, j0 = bj * 128;
  const int wave = tid >> 6, lane = tid & 63;
  const int wr = wave >> 1, wc = wave & 1;
  const int l16 = lane & 15, lq = lane >> 4;

  f32x4 acc[4][4] = {};
  for (int kk = 0; kk < H; kk += 64) {
    #pragma unroll
    for (int it = 0; it < 8; ++it) {
      int q = it * 256 + tid;
      int r = q >> 4, c4 = (q & 15) << 2;
      f32x4 v = *(const f32x4*)&x[(size_t)(i0 + r) * H + kk + c4];
      bf16x4v o;
      #pragma unroll
      for (int j = 0; j < 4; ++j) o[j] = (short)f2bf(v[j]);
      *(bf16x4v*)&As[r * 72 + c4] = o;
    }
    #pragma unroll
    for (int it = 0; it < 4; ++it) {
      int q = it * 256 + tid;
      int r = q >> 3, c8 = (q & 7) << 3;
      *(bf16x8*)&Bs[r * 72 + c8] = *(const bf16x8*)&Wt[(size_t)(j0 + r) * H + kk + c8];
    }
    __syncthreads();
    #pragma unroll
    for (int s = 0; s < 2; ++s) {
      bf16x8 af[4], bfr[4];
      #pragma unroll
      for (int mi = 0; mi < 4; ++mi)
        af[mi] = *(const bf16x8*)&As[(wr * 64 + mi * 16 + l16) * 72 + s * 32 + lq * 8];
      #pragma unroll
      for (int ni = 0; ni < 4; ++ni)
        bfr[ni] = *(const bf16x8*)&Bs[(wc * 64 + ni * 16 + l16) * 72 + s * 32 + lq * 8];
      #pragma unroll
      for (int mi = 0; mi < 4; ++mi)
        #pragma unroll
        for (int ni = 0; ni < 4; ++ni)
          acc[mi][ni] = __builtin_amdgcn_mfma_f32_16x16x32_bf16(af[mi], bfr[ni], acc[mi][ni], 0, 0, 0);
    }
    __syncthreads();
  }
  float* ep = Es + wave * (16 * EPAD);
  const int rr = lane >> 2;
  const int cq = (lane & 3) * 16;
  #pragma unroll
  for (int mi = 0; mi < 4; ++mi) {
    #pragma unroll
    for (int ni = 0; ni < 4; ++ni)
      #pragma unroll
      for (int r = 0; r < 4; ++r)
        ep[(lq * 4 + r) * EPAD + ni * 16 + l16] = acc[mi][ni][r];
    const int i  = i0 + wr * 64 + mi * 16 + rr;
    const int jb = j0 + wc * 64 + cq;
    const float* xrow = &x[(size_t)i * H + jb];
    float*       orow = &out[(size_t)i * H + jb];
    #pragma unroll
    for (int t = 0; t < 4; ++t) {
      f32x4 a  = *(const f32x4*)&ep[rr * EPAD + cq + 4 * t];
      f32x4 xv = *(const f32x4*)&xrow[4 * t];
      f32x4 b4 = *(const f32x4*)&bv[jb + 4 * t];
      f32x4 c4 = *(const f32x4*)&cv[jb + 4 * t];
      f32x4 d4 = *(const f32x4*)&dv[jb + 4 * t];
      f32x4 o;
      #pragma unroll
      for (int e = 0; e < 4; ++e) {
        float s, co;
        my_sincos(xv[e], s, co);
        const float tanv = s * __builtin_amdgcn_rcpf(co);
        o[e] = S * (fmaf(b4[e], s, a[e]) + fmaf(c4[e], co, d4[e] * tanv));
      }
      *(f32x4*)&orow[4 * t] = o;
    }
  }
}

extern "C" void kernel_launch(void* const* d_in, const int* in_sizes, int n_in,
                              void* d_out, int out_size, void* d_ws, size_t ws_size,
                              hipStream_t stream) {
  const float* x = (const float*)d_in[0];
  const float* W = (const float*)d_in[1];
  const float* b = (const float*)d_in[2];
  const float* c = (const float*)d_in[3];
  const float* d = (const float*)d_in[4];
  float* out = (float*)d_out;
  const int H = in_sizes[2];          // 1024
  const int M = in_sizes[0] / H;      // 16384

  // Scalar RK4 factor: y_final = S * z (ODE linear in y, y0 = 0).
  const int NT = 100;
  float ts[NT];
  const float step = (float)(1.0 / 99.0);
  for (int i = 0; i < NT; ++i) ts[i] = (float)i * step;
  ts[NT - 1] = 1.0f;
  double yy = 0.0;
  for (int i = 0; i < NT - 1; ++i) {
    const double t = (double)ts[i], dt = (double)(ts[i + 1] - ts[i]);
    const double k1 = t - yy;
    const double k2 = (t + 0.5 * dt) - (yy + 0.5 * dt * k1);
    const double k3 = (t + 0.5 * dt) - (yy + 0.5 * dt * k2);
    const double k4 = (t + dt) - (yy + dt * k3);
    yy += dt / 6.0 * (k1 + 2.0 * k2 + 2.0 * k3 + k4);
  }
  const float S = (float)yy;

  unsigned short* Wt = (unsigned short*)d_ws;                 // 2 MB bf16 W^T
  const int nblk = (M / 256) * (H / 128);                     // 512
  const bool shapeOK = (H % 128 == 0) && (M % 256 == 0) && (nblk % 8 == 0)
                    && (H % 64 == 0);

  dim3 tgrid(H / 64, H / 64);
  transpose_W<<<tgrid, 256, 0, stream>>>(W, Wt, H);

  if (shapeOK) {
    gemm_fused256<<<nblk, 512, 0, stream>>>(x, Wt, b, c, d, out, S, H);
  } else {
    gemm_fb<<<(H / 128) * (M / 128), 256, 0, stream>>>(x, Wt, b, c, d, out, S, H);
  }
}